// Round 1
// baseline (771.169 us; speedup 1.0000x reference)
//
#include <hip/hip_runtime.h>

#define B_ 256
#define T_ 2048
#define H_ 64

typedef float f32x2 __attribute__((ext_vector_type(2)));
typedef float f32x4 __attribute__((ext_vector_type(4)));

__device__ __forceinline__ float fast_sigmoid(float v) {
    // 1/(1+e^-v) = rcp(1 + exp2(-v*log2(e)))
    float e = __builtin_amdgcn_exp2f(-1.4426950408889634f * v);
    return __builtin_amdgcn_rcpf(1.0f + e);
}

__device__ __forceinline__ float fast_tanh(float v) {
    // tanh(v) = 1 - 2/(1 + e^(2v))
    float e = __builtin_amdgcn_exp2f(2.8853900817779268f * v);
    return fmaf(-2.0f, __builtin_amdgcn_rcpf(1.0f + e), 1.0f);
}

__global__ __launch_bounds__(192, 1)
void gru_kernel(const float* __restrict__ x,
                const float* __restrict__ W_ih,
                const float* __restrict__ W_hh,
                const float* __restrict__ b_ih,
                const float* __restrict__ b_hh,
                float* __restrict__ out)
{
    // gate exchange: double buffered [t&1][gate][channel]
    __shared__ float sg[2][3][64];
    // per-wave private h broadcast buffer, double buffered
    __shared__ float sh[3][2][64];

    const int tid  = threadIdx.x;
    const int lane = tid & 63;
    const int w    = tid >> 6;          // 0=r, 1=z, 2=n
    const int b    = blockIdx.x;
    const int g    = w * 64 + lane;     // my row of W_hh

    // ---- preload W_hh row g into 32 float2 register pairs ----
    f32x2 w2[32];
    {
        const f32x4* wrow = (const f32x4*)(W_hh + g * H_);
        #pragma unroll
        for (int q = 0; q < 16; ++q) {
            f32x4 v = wrow[q];
            w2[2*q]     = f32x2{v.x, v.y};
            w2[2*q + 1] = f32x2{v.z, v.w};
        }
    }

    const float wih  = W_ih[g];
    const float preb = (w < 2) ? (b_ih[g] + b_hh[g]) : b_hh[g];
    // every lane needs the n-gate input-side params for its channel
    const float wih_n = W_ih[128 + lane];
    const float bih_n = b_ih[128 + lane];

    const float* __restrict__ xrow = x + (size_t)b * T_;
    float* __restrict__ orow = out + (size_t)b * T_;

    // replicated h (all 64 channels in every lane), starts at 0
    f32x2 h2[32];
    #pragma unroll
    for (int i = 0; i < 32; ++i) h2[i] = f32x2{0.0f, 0.0f};
    float h_own = 0.0f;   // lane j's own channel value
    float oval  = 0.0f;   // staged output for coalesced store

    for (int t = 0; t < T_; ++t) {
        const float xt = xrow[t];           // workgroup-uniform -> s_load
        const int pb = t & 1;

        // ---- phase 1: my gate's pre-activation: sum_k W[g][k] * h[k] ----
        f32x2 a0 = {0.f, 0.f}, a1 = {0.f, 0.f}, a2 = {0.f, 0.f}, a3 = {0.f, 0.f};
        #pragma unroll
        for (int k = 0; k < 32; k += 4) {
            a0 += w2[k]     * h2[k];
            a1 += w2[k + 1] * h2[k + 1];
            a2 += w2[k + 2] * h2[k + 2];
            a3 += w2[k + 3] * h2[k + 3];
        }
        f32x2 s = (a0 + a1) + (a2 + a3);
        float pre = (w < 2) ? fmaf(xt, wih, preb) : preb;
        float dot = s.x + s.y + pre;
        // r,z: full sigmoid; n: keep linear h-side term (r*(Wn h + bhh_n) later)
        float gval = (w < 2) ? fast_sigmoid(dot) : dot;

        sg[pb][w][lane] = gval;
        __syncthreads();

        // ---- phase 2 (redundant in all waves): combine gates ----
        float r  = sg[pb][0][lane];
        float z  = sg[pb][1][lane];
        float hn = sg[pb][2][lane];
        float xn = fmaf(xt, wih_n, bih_n);
        float n  = fast_tanh(fmaf(r, hn, xn));
        float h_new = n + z * (h_own - n);  // (1-z)*n + z*h
        h_own = h_new;

        // ---- rebuild replicated h via wave-private LDS broadcast ----
        sh[w][pb][lane] = h_new;
        __builtin_amdgcn_wave_barrier();    // keep write before reads (same wave)
        {
            const f32x4* hp = (const f32x4*)sh[w][pb];
            #pragma unroll
            for (int q = 0; q < 16; ++q) {
                f32x4 v = hp[q];            // broadcast ds_read_b128
                h2[2*q]     = f32x2{v.x, v.y};
                h2[2*q + 1] = f32x2{v.z, v.w};
            }
        }

        // ---- stage output: h_new[63] is h2[31].y (static reg) in all lanes ----
        float h63 = h2[31].y;
        oval = ((t & 63) == lane) ? h63 : oval;
        if ((t & 63) == 63 && w == 0) {
            orow[(t & ~63) + lane] = oval;  // coalesced 256B store per 64 steps
        }
    }
}

extern "C" void kernel_launch(void* const* d_in, const int* in_sizes, int n_in,
                              void* d_out, int out_size, void* d_ws, size_t ws_size,
                              hipStream_t stream) {
    const float* x    = (const float*)d_in[0];
    const float* W_ih = (const float*)d_in[1];
    const float* W_hh = (const float*)d_in[2];
    const float* b_ih = (const float*)d_in[3];
    const float* b_hh = (const float*)d_in[4];
    float* out = (float*)d_out;

    dim3 grid(B_), block(192);
    gru_kernel<<<grid, block, 0, stream>>>(x, W_ih, W_hh, b_ih, b_hh, out);
}